// Round 4
// baseline (8490.025 us; speedup 1.0000x reference)
//
#include <hip/hip_runtime.h>
#include <stdint.h>

typedef _Float16 f16;
typedef f16 v8h __attribute__((ext_vector_type(8)));
typedef f16 v4h __attribute__((ext_vector_type(4)));
typedef float v4f __attribute__((ext_vector_type(4)));

#define B_   64
#define L_   49
#define ENC_ 2048
#define D_   512
#define V_   10000
#define T_   60
#define TM_  59
#define NBLK 144

__device__ __forceinline__ float sigmoidf_(float x) { return 1.f / (1.f + __expf(-x)); }
__device__ __forceinline__ float tanhf_(float x) {
  float e2 = __expf(2.f * x);
  return 1.f - 2.f / (e2 + 1.f);
}

// ---- manual grid barrier: device-scope atomics, all NBLK blocks co-resident ----
__device__ __forceinline__ void gridbar(int* cnt, int* gen, int* my_gen) {
  __syncthreads();
  if (threadIdx.x == 0) {
    __threadfence();                       // publish this block's writes
    int g = *my_gen;
    if (atomicAdd(cnt, 1) == NBLK - 1) {
      atomicExch(cnt, 0);                  // reset before release
      atomicAdd(gen, 1);                   // release
    } else {
      while (atomicAdd(gen, 0) == g) __builtin_amdgcn_s_sleep(2);
    }
    *my_gen = g + 1;
    __threadfence();                       // acquire: invalidate stale caches
  }
  __syncthreads();
}

// ---------------- one-shot f32 -> f16 casts (6 arrays) ----------------
struct CastJobs { const float* s[6]; f16* d[6]; int n4[6]; };
__global__ __launch_bounds__(256) void k_cast(CastJobs J) {
  int a = blockIdx.y;
  int i = blockIdx.x * 256 + threadIdx.x;
  if (i >= J.n4[a]) return;
  float4 v = ((const float4*)J.s[a])[i];
  v4h o; o[0] = (f16)v.x; o[1] = (f16)v.y; o[2] = (f16)v.z; o[3] = (f16)v.w;
  ((v4h*)J.d[a])[i] = o;
}

// ---------------- pack W1 = [dec_att_w | actv_w | whh] as f16 [512][4608] ----------------
__global__ __launch_bounds__(256) void k_pack(const float* __restrict__ dw,
    const float* __restrict__ aw, const float* __restrict__ ww,
    f16* __restrict__ W1) {
  int i4 = (blockIdx.x * 256 + threadIdx.x) * 4;   // < 2359296
  int k = i4 / 4608, col = i4 % 4608;
  const float* src; int scol;
  if (col < 512)       { src = dw + (size_t)k * 512;  scol = col; }
  else if (col < 2560) { src = aw + (size_t)k * 2048; scol = col - 512; }
  else                 { src = ww + (size_t)k * 2048; scol = col - 2560; }
  float4 v = *(const float4*)(src + scol);
  v4h o; o[0] = (f16)v.x; o[1] = (f16)v.y; o[2] = (f16)v.z; o[3] = (f16)v.w;
  *(v4h*)(W1 + i4) = o;
}

// ---------------- mean over L ----------------
__global__ __launch_bounds__(256) void k_mean(const f16* __restrict__ inh,
                                              f16* __restrict__ meanh) {
  int b = blockIdx.x, tid = threadIdx.x;
  for (int e = tid; e < ENC_; e += 256) {
    float s = 0.f;
    for (int l = 0; l < L_; l++) s += (float)inh[((size_t)(b * L_ + l)) * ENC_ + e];
    meanh[b * ENC_ + e] = (f16)(s * (1.f / 49.f));
  }
}

// ---------------- shared 64x64 f16 MFMA tile helpers ----------------
__device__ __forceinline__ void stage_a64(const f16* src, int lda, f16 (*sA)[72], int tid) {
  int ar = tid >> 2, ak = (tid & 3) << 4;
  const f16* p = src + (size_t)ar * lda + ak;
  *(uint4*)&sA[ar][ak]     = *(const uint4*)p;
  *(uint4*)&sA[ar][ak + 8] = *(const uint4*)(p + 8);
}
__device__ __forceinline__ void stage_b64(const f16* src, int ldb, f16 (*sB)[72], int tid) {
  #pragma unroll
  for (int s = 0; s < 4; s++) {
    int slot = tid + s * 256;
    int kr = slot >> 4, nc = (slot & 15) << 2;
    v4h bl = *(const v4h*)(src + (size_t)kr * ldb + nc);
    sB[nc + 0][kr] = bl[0]; sB[nc + 1][kr] = bl[1];
    sB[nc + 2][kr] = bl[2]; sB[nc + 3][kr] = bl[3];
  }
}
__device__ __forceinline__ void mfma_tile(const f16 (*sA)[72], const f16 (*sB)[72],
                                          int fr, int fq, int wv, v4f* acc) {
  #pragma unroll
  for (int kk = 0; kk < 64; kk += 32) {
    v8h bfr = *(const v8h*)&sB[wv * 16 + fr][kk + fq * 8];
    #pragma unroll
    for (int mt = 0; mt < 4; mt++) {
      v8h afr = *(const v8h*)&sA[mt * 16 + fr][kk + fq * 8];
      acc[mt] = __builtin_amdgcn_mfma_f32_16x16x32_f16(afr, bfr, acc[mt], 0, 0, 0);
    }
  }
}

// ---------------- h0/c0 (MFMA) ----------------
__global__ __launch_bounds__(256) void k_h0c0(const f16* __restrict__ meanh,
    const f16* __restrict__ hw, const float* __restrict__ hb,
    const f16* __restrict__ cw, const float* __restrict__ cb,
    float* __restrict__ h, float* __restrict__ c, f16* __restrict__ hh) {
  __shared__ __align__(16) f16 sA[64][72], sB[64][72];
  int tid = threadIdx.x, lane = tid & 63, wv = tid >> 6, fr = lane & 15, fq = lane >> 4;
  int n0 = blockIdx.x * 64;
  bool ish = n0 < 512;
  const f16* W = ish ? hw : cw;
  const float* bb = ish ? hb : cb;
  int nb = ish ? n0 : (n0 - 512);
  v4f acc[4] = {};
  for (int k0 = 0; k0 < 2048; k0 += 64) {
    stage_a64(meanh + k0, 2048, sA, tid);
    stage_b64(W + (size_t)k0 * 512 + nb, 512, sB, tid);
    __syncthreads(); mfma_tile(sA, sB, fr, fq, wv, acc); __syncthreads();
  }
  int col = nb + wv * 16 + fr;
  float bv = bb[col];
  #pragma unroll
  for (int mt = 0; mt < 4; mt++)
    #pragma unroll
    for (int r = 0; r < 4; r++) {
      int b = mt * 16 + fq * 4 + r;
      float v = acc[mt][r] + bv;
      if (ish) { h[b * 512 + col] = v; hh[b * 512 + col] = (f16)v; }
      else       c[b * 512 + col] = v;
    }
}

// ---------------- enc_proj (MFMA, f16 out) ----------------
__global__ __launch_bounds__(256) void k_ep(const f16* __restrict__ inh,
    const f16* __restrict__ Wh, const float* __restrict__ bias,
    f16* __restrict__ out) {
  __shared__ __align__(16) f16 sA[64][72], sB[64][72];
  int tid = threadIdx.x, lane = tid & 63, wv = tid >> 6, fr = lane & 15, fq = lane >> 4;
  int m0 = blockIdx.x * 64, n0 = blockIdx.y * 64;
  v4f acc[4] = {};
  for (int k0 = 0; k0 < 2048; k0 += 64) {
    stage_a64(inh + (size_t)m0 * 2048 + k0, 2048, sA, tid);
    stage_b64(Wh + (size_t)k0 * 512 + n0, 512, sB, tid);
    __syncthreads(); mfma_tile(sA, sB, fr, fq, wv, acc); __syncthreads();
  }
  int col = n0 + wv * 16 + fr;
  float bv = bias[col];
  #pragma unroll
  for (int mt = 0; mt < 4; mt++)
    #pragma unroll
    for (int r = 0; r < 4; r++)
      out[(size_t)(m0 + mt * 16 + fq * 4 + r) * 512 + col] = (f16)(acc[mt][r] + bv);
}

// ---------------- emb gather (f16) ----------------
__global__ __launch_bounds__(256) void k_gather(const int* __restrict__ captions,
    const float* __restrict__ embw, f16* __restrict__ embx) {
  int t = blockIdx.x, b = blockIdx.y;
  int cap = captions[b * T_ + t];
  const float* src = embw + (size_t)cap * 512;
  f16* dst = embx + ((size_t)t * 64 + b) * 512;
  for (int i = threadIdx.x; i < 512; i += 256) dst[i] = (f16)src[i];
}

// ---------------- embproj = embx @ wih[0:512] + bih + bhh  (f16 out) ----------------
__global__ __launch_bounds__(256) void k_embproj(const f16* __restrict__ embx,
    const f16* __restrict__ wih_h, const float* __restrict__ bih,
    const float* __restrict__ bhh, f16* __restrict__ embproj) {
  __shared__ __align__(16) f16 sA[64][72], sB[64][72];
  int tid = threadIdx.x, lane = tid & 63, wv = tid >> 6, fr = lane & 15, fq = lane >> 4;
  int m0 = blockIdx.x * 64, n0 = blockIdx.y * 64;
  v4f acc[4] = {};
  for (int k0 = 0; k0 < 512; k0 += 64) {
    stage_a64(embx + (size_t)m0 * 512 + k0, 512, sA, tid);
    stage_b64(wih_h + (size_t)k0 * 2048 + n0, 2048, sB, tid);
    __syncthreads(); mfma_tile(sA, sB, fr, fq, wv, acc); __syncthreads();
  }
  int col = n0 + wv * 16 + fr;
  float bv = bih[col] + bhh[col];
  #pragma unroll
  for (int mt = 0; mt < 4; mt++)
    #pragma unroll
    for (int r = 0; r < 4; r++)
      embproj[(size_t)(m0 + mt * 16 + fq * 4 + r) * 2048 + col] = (f16)(acc[mt][r] + bv);
}

// ---------------- persistent recurrence (plain launch + manual grid barrier) ----------------
__global__ __launch_bounds__(256) void k_loop(
    const f16* __restrict__ input_h, const f16* __restrict__ encproj,
    const f16* __restrict__ W1, const f16* __restrict__ wih2,
    const f16* __restrict__ embproj, const float* __restrict__ att_w,
    const float* __restrict__ att_b, const float* __restrict__ dab,
    const float* __restrict__ avb, const int* __restrict__ lens,
    float* __restrict__ hf, float* __restrict__ cf, f16* __restrict__ hh,
    float* __restrict__ pp1, f16* __restrict__ xg, float* __restrict__ q,
    f16* __restrict__ hseq, float* __restrict__ probs, int* bar) {
  __shared__ __align__(16) f16 sA[64][72], sB[64][72];
  __shared__ float sd[512], sw[512], ss[64], sp[64];
  int bid = blockIdx.x, tid = threadIdx.x;
  int lane = tid & 63, wv = tid >> 6, fr = lane & 15, fq = lane >> 4;
  int* cnt = bar; int* gen = bar + 1;
  int my_gen = 0;

  if (bid < 128)
    for (int i = tid; i < 512; i += 256) sw[i] = att_w[i];
  float attb = att_b[0];

  for (int t = 0; t < TM_; t++) {
    // ---- P1 (all 144 blocks): pp1[z] = hh[:, z*256:+256] @ W1[z rows][4608] ----
    {
      int z = bid & 1, n0 = (bid >> 1) * 64;
      v4f acc[4] = {};
      #pragma unroll
      for (int ch = 0; ch < 4; ch++) {
        int k0 = z * 256 + ch * 64;
        stage_a64(hh + k0, 512, sA, tid);
        stage_b64(W1 + (size_t)k0 * 4608 + n0, 4608, sB, tid);
        __syncthreads(); mfma_tile(sA, sB, fr, fq, wv, acc); __syncthreads();
      }
      int col = n0 + wv * 16 + fr;
      float* pp = pp1 + (size_t)z * 64 * 4608;
      #pragma unroll
      for (int mt = 0; mt < 4; mt++)
        #pragma unroll
        for (int r = 0; r < 4; r++)
          pp[(size_t)(mt * 16 + fq * 4 + r) * 4608 + col] = acc[mt][r];
    }
    gridbar(cnt, gen, &my_gen);
    // ---- P2 (128 blocks): attention + x staging ----
    if (bid < 128) {
      int b = bid >> 1, half = bid & 1;
      for (int i = tid; i < 512; i += 256)
        sd[i] = pp1[b * 4608 + i] + pp1[(size_t)64 * 4608 + b * 4608 + i] + dab[i];
      __syncthreads();
      for (int l = wv; l < L_; l += 4) {
        const f16* ep = encproj + (size_t)(b * L_ + l) * 512;
        float p = 0.f;
        #pragma unroll
        for (int i = 0; i < 8; i++) {
          int a = lane + i * 64;
          float v = (float)ep[a] + sd[a];
          p = fmaf(fmaxf(v, 0.f), sw[a], p);
        }
        #pragma unroll
        for (int off = 32; off > 0; off >>= 1) p += __shfl_xor(p, off);
        if (lane == 0) ss[l] = p;
      }
      __syncthreads();
      if (wv == 0) {
        float v = (lane < L_) ? (ss[lane] + attb) : -3.0e38f;
        float m = v;
        #pragma unroll
        for (int off = 32; off > 0; off >>= 1) m = fmaxf(m, __shfl_xor(m, off));
        float e = (lane < L_) ? __expf(v - m) : 0.f;
        float s = e;
        #pragma unroll
        for (int off = 32; off > 0; off >>= 1) s += __shfl_xor(s, off);
        float pr = e / s;
        if (lane < L_) {
          sp[lane] = pr;
          if (half == 0) {
            bool act = t < (lens[b] - 1);
            probs[((size_t)b * TM_ + t) * L_ + lane] = act ? pr : 0.f;
          }
        }
      }
      __syncthreads();
      int c = half * 1024 + tid * 4;
      const f16* ip = input_h + (size_t)b * L_ * 2048 + c;
      float a0 = 0, a1 = 0, a2 = 0, a3 = 0;
      for (int l = 0; l < L_; l++) {
        v4h x = *(const v4h*)(ip + (size_t)l * 2048);
        float pl = sp[l];
        a0 = fmaf(pl, (float)x[0], a0); a1 = fmaf(pl, (float)x[1], a1);
        a2 = fmaf(pl, (float)x[2], a2); a3 = fmaf(pl, (float)x[3], a3);
      }
      const float* g0 = pp1 + b * 4608 + 512 + c;
      const float* g1 = pp1 + (size_t)64 * 4608 + b * 4608 + 512 + c;
      float4 u = *(const float4*)g0, v4 = *(const float4*)g1;
      float4 ab = *(const float4*)(avb + c);
      v4h o;
      o[0] = (f16)(a0 * sigmoidf_(u.x + v4.x + ab.x));
      o[1] = (f16)(a1 * sigmoidf_(u.y + v4.y + ab.y));
      o[2] = (f16)(a2 * sigmoidf_(u.z + v4.z + ab.z));
      o[3] = (f16)(a3 * sigmoidf_(u.w + v4.w + ab.w));
      *(v4h*)(xg + b * 2048 + c) = o;
    }
    gridbar(cnt, gen, &my_gen);
    // ---- P3 (128 blocks): q[z] = xg[:, z*512:+512] @ wih2[z rows] ----
    if (bid < 128) {
      int z = bid & 3, n0 = (bid >> 2) * 64;
      v4f acc[4] = {};
      #pragma unroll
      for (int ch = 0; ch < 8; ch++) {
        int k0 = z * 512 + ch * 64;
        stage_a64(xg + k0, 2048, sA, tid);
        stage_b64(wih2 + (size_t)k0 * 2048 + n0, 2048, sB, tid);
        __syncthreads(); mfma_tile(sA, sB, fr, fq, wv, acc); __syncthreads();
      }
      int col = n0 + wv * 16 + fr;
      float* qq = q + (size_t)z * 64 * 2048;
      #pragma unroll
      for (int mt = 0; mt < 4; mt++)
        #pragma unroll
        for (int r = 0; r < 4; r++)
          qq[(size_t)(mt * 16 + fq * 4 + r) * 2048 + col] = acc[mt][r];
    }
    gridbar(cnt, gen, &my_gen);
    // ---- P4 (32 blocks): reduce + cell update ----
    if (bid < 32) {
      #pragma unroll
      for (int it = 0; it < 4; it++) {
        int idx = it * 256 + tid;
        int b = bid * 2 + (idx >> 9);
        int d = idx & 511;
        float g4[4];
        #pragma unroll
        for (int gate = 0; gate < 4; gate++) {
          int n = gate * 512 + d;
          float s = (float)embproj[((size_t)t * 64 + b) * 2048 + n];
          s += pp1[b * 4608 + 2560 + n] + pp1[(size_t)64 * 4608 + b * 4608 + 2560 + n];
          #pragma unroll
          for (int z = 0; z < 4; z++) s += q[((size_t)z * 64 + b) * 2048 + n];
          g4[gate] = s;
        }
        float i_ = sigmoidf_(g4[0]), f_ = sigmoidf_(g4[1]);
        float gg = tanhf_(g4[2]), o_ = sigmoidf_(g4[3]);
        float cold = cf[b * 512 + d], hold = hf[b * 512 + d];
        float cn = f_ * cold + i_ * gg;
        float hn = o_ * tanhf_(cn);
        bool act = t < (lens[b] - 1);
        float ho = act ? hn : hold, co = act ? cn : cold;
        hf[b * 512 + d] = ho; cf[b * 512 + d] = co;
        hh[b * 512 + d] = (f16)ho;
        hseq[((size_t)t * 64 + b) * 512 + d] = (f16)ho;
      }
    }
    gridbar(cnt, gen, &my_gen);
  }
}

// ---------------- final fc GEMM ----------------
__global__ __launch_bounds__(256) void k_fc(const f16* __restrict__ hseq,
    const f16* __restrict__ W, const float* __restrict__ bias,
    const int* __restrict__ lens, float* __restrict__ preds) {
  __shared__ __align__(16) f16 sA[64][72], sB[64][72];
  int tid = threadIdx.x, lane = tid & 63, wv = tid >> 6, fr = lane & 15, fq = lane >> 4;
  int t = blockIdx.x, n0 = blockIdx.y * 64;
  v4f acc[4] = {};
  for (int k0 = 0; k0 < 512; k0 += 64) {
    stage_a64(hseq + ((size_t)t * 64) * 512 + k0, 512, sA, tid);
    #pragma unroll
    for (int s = 0; s < 4; s++) {
      int slot = tid + s * 256;
      int kr = slot >> 4, nc = (slot & 15) << 2;
      int colb = n0 + nc;
      const f16* bp = W + (size_t)(k0 + kr) * V_;
      f16 e0, e1, e2, e3;
      if (colb + 3 < V_) {
        v4h bl = *(const v4h*)(bp + colb);
        e0 = bl[0]; e1 = bl[1]; e2 = bl[2]; e3 = bl[3];
      } else {
        e0 = (colb + 0 < V_) ? bp[colb + 0] : (f16)0.f;
        e1 = (colb + 1 < V_) ? bp[colb + 1] : (f16)0.f;
        e2 = (colb + 2 < V_) ? bp[colb + 2] : (f16)0.f;
        e3 = (colb + 3 < V_) ? bp[colb + 3] : (f16)0.f;
      }
      sB[nc + 0][kr] = e0; sB[nc + 1][kr] = e1; sB[nc + 2][kr] = e2; sB[nc + 3][kr] = e3;
    }
    __syncthreads(); mfma_tile(sA, sB, fr, fq, wv, acc); __syncthreads();
  }
  int col = n0 + wv * 16 + fr;
  if (col < V_) {
    float bv = bias[col];
    #pragma unroll
    for (int mt = 0; mt < 4; mt++)
      #pragma unroll
      for (int r = 0; r < 4; r++) {
        int b = mt * 16 + fq * 4 + r;
        bool act = t < (lens[b] - 1);
        preds[((size_t)b * TM_ + t) * (size_t)V_ + col] = act ? (acc[mt][r] + bv) : 0.f;
      }
  }
}

extern "C" void kernel_launch(void* const* d_in, const int* in_sizes, int n_in,
                              void* d_out, int out_size, void* d_ws, size_t ws_size,
                              hipStream_t stream) {
  (void)in_sizes; (void)n_in; (void)out_size; (void)ws_size;
  const float* input     = (const float*)d_in[0];
  const int*   captions  = (const int*)d_in[1];
  const int*   lens      = (const int*)d_in[2];
  const float* embw      = (const float*)d_in[3];
  const float* enc_att_w = (const float*)d_in[4];
  const float* enc_att_b = (const float*)d_in[5];
  const float* dec_att_w = (const float*)d_in[6];
  const float* dec_att_b = (const float*)d_in[7];
  const float* att_w     = (const float*)d_in[8];
  const float* att_b     = (const float*)d_in[9];
  const float* h_w       = (const float*)d_in[10];
  const float* h_b       = (const float*)d_in[11];
  const float* c_w       = (const float*)d_in[12];
  const float* c_b       = (const float*)d_in[13];
  const float* actv_w    = (const float*)d_in[14];
  const float* actv_b    = (const float*)d_in[15];
  const float* wih       = (const float*)d_in[16];
  const float* whh       = (const float*)d_in[17];
  const float* bih       = (const float*)d_in[18];
  const float* bhh       = (const float*)d_in[19];
  const float* fc_w      = (const float*)d_in[20];
  const float* fc_b      = (const float*)d_in[21];

  float* preds = (float*)d_out;
  float* probs = preds + (size_t)B_ * TM_ * V_;

  char* w = (char*)d_ws;
  auto alloc = [&](size_t bytes) -> char* {
    char* p = w; w += (bytes + 255) & ~(size_t)255; return p;
  };
  int* bar     = (int*)alloc(256);
  f16* input_h = (f16*)alloc((size_t)6422528 * 2);
  f16* eaw_h   = (f16*)alloc((size_t)1048576 * 2);
  f16* wih_h   = (f16*)alloc((size_t)5242880 * 2);
  f16* hw_h    = (f16*)alloc((size_t)1048576 * 2);
  f16* cw_h    = (f16*)alloc((size_t)1048576 * 2);
  f16* fcw_h   = (f16*)alloc((size_t)5120000 * 2);
  f16* W1      = (f16*)alloc((size_t)2359296 * 2);
  f16* meanh   = (f16*)alloc((size_t)B_ * ENC_ * 2);
  f16* encproj = (f16*)alloc((size_t)3136 * 512 * 2);
  f16* embx    = (f16*)alloc((size_t)3776 * 512 * 2);
  f16* embproj = (f16*)alloc((size_t)3776 * 2048 * 2);
  float* hf    = (float*)alloc((size_t)B_ * 512 * 4);
  float* cf    = (float*)alloc((size_t)B_ * 512 * 4);
  f16*   hh    = (f16*)alloc((size_t)B_ * 512 * 2);
  float* pp1   = (float*)alloc((size_t)2 * 64 * 4608 * 4);
  f16*   xg    = (f16*)alloc((size_t)B_ * 2048 * 2);
  float* q     = (float*)alloc((size_t)4 * 64 * 2048 * 4);
  f16*   hseq  = (f16*)alloc((size_t)TM_ * 64 * 512 * 2);

  hipMemsetAsync(bar, 0, 8, stream);

  CastJobs J;
  J.s[0] = input; J.d[0] = input_h; J.n4[0] = 6422528 / 4;
  J.s[1] = enc_att_w; J.d[1] = eaw_h; J.n4[1] = 1048576 / 4;
  J.s[2] = wih; J.d[2] = wih_h; J.n4[2] = 5242880 / 4;
  J.s[3] = h_w; J.d[3] = hw_h; J.n4[3] = 1048576 / 4;
  J.s[4] = c_w; J.d[4] = cw_h; J.n4[4] = 1048576 / 4;
  J.s[5] = fc_w; J.d[5] = fcw_h; J.n4[5] = 5120000 / 4;
  k_cast<<<dim3((1605632 + 255) / 256, 6), 256, 0, stream>>>(J);
  k_pack<<<2304, 256, 0, stream>>>(dec_att_w, actv_w, whh, W1);
  k_mean<<<64, 256, 0, stream>>>(input_h, meanh);
  k_h0c0<<<16, 256, 0, stream>>>(meanh, hw_h, h_b, cw_h, c_b, hf, cf, hh);
  k_ep<<<dim3(49, 8), 256, 0, stream>>>(input_h, eaw_h, enc_att_b, encproj);
  k_gather<<<dim3(59, 64), 256, 0, stream>>>(captions, embw, embx);
  k_embproj<<<dim3(59, 32), 256, 0, stream>>>(embx, wih_h, bih, bhh, embproj);

  const f16* wih2 = wih_h + (size_t)512 * 2048;
  k_loop<<<NBLK, 256, 0, stream>>>(input_h, encproj, W1, wih2, embproj,
                                   att_w, att_b, dec_att_b, actv_b, lens,
                                   hf, cf, hh, pp1, xg, q, hseq, probs, bar);

  k_fc<<<dim3(59, 157), 256, 0, stream>>>(hseq, fcw_h, fc_b, lens, preds);
}

// Round 5
// 4799.678 us; speedup vs baseline: 1.7689x; 1.7689x over previous
//
#include <hip/hip_runtime.h>
#include <stdint.h>

typedef _Float16 f16;
typedef f16 v8h __attribute__((ext_vector_type(8)));
typedef f16 v4h __attribute__((ext_vector_type(4)));
typedef float v4f __attribute__((ext_vector_type(4)));

#define B_   64
#define L_   49
#define ENC_ 2048
#define D_   512
#define V_   10000
#define T_   60
#define TM_  59
#define NBLK 144

__device__ __forceinline__ float sigmoidf_(float x) { return 1.f / (1.f + __expf(-x)); }
__device__ __forceinline__ float tanhf_(float x) {
  float e2 = __expf(2.f * x);
  return 1.f - 2.f / (e2 + 1.f);
}

// ---- agent-scope (cross-XCD coherent, cache-bypassing) accessors ----
__device__ __forceinline__ float ld_sc_f32(const float* p) {
  return __hip_atomic_load(p, __ATOMIC_RELAXED, __HIP_MEMORY_SCOPE_AGENT);
}
__device__ __forceinline__ void st_sc_f32(float* p, float v) {
  __hip_atomic_store(p, v, __ATOMIC_RELAXED, __HIP_MEMORY_SCOPE_AGENT);
}
__device__ __forceinline__ unsigned long long ld_sc_u64(const void* p) {
  return __hip_atomic_load((const unsigned long long*)p, __ATOMIC_RELAXED, __HIP_MEMORY_SCOPE_AGENT);
}
__device__ __forceinline__ void st_sc_u64(void* p, unsigned long long v) {
  __hip_atomic_store((unsigned long long*)p, v, __ATOMIC_RELAXED, __HIP_MEMORY_SCOPE_AGENT);
}
__device__ __forceinline__ void st_sc_u32(void* p, uint32_t v) {
  __hip_atomic_store((uint32_t*)p, v, __ATOMIC_RELAXED, __HIP_MEMORY_SCOPE_AGENT);
}
__device__ __forceinline__ float2 u64_f2(unsigned long long u) {
  float2 f; __builtin_memcpy(&f, &u, 8); return f;
}
__device__ __forceinline__ uint32_t pack_f16x2(float a, float b) {
  f16 h0 = (f16)a, h1 = (f16)b; unsigned short s0, s1;
  __builtin_memcpy(&s0, &h0, 2); __builtin_memcpy(&s1, &h1, 2);
  return (uint32_t)s0 | ((uint32_t)s1 << 16);
}
__device__ __forceinline__ float2 f16x2_f2(uint32_t u) {
  unsigned short s0 = u & 0xffff, s1 = u >> 16; f16 h0, h1;
  __builtin_memcpy(&h0, &s0, 2); __builtin_memcpy(&h1, &s1, 2);
  return make_float2((float)h0, (float)h1);
}

// ---- fence-free grid barrier: per-wave vm drain + relaxed agent atomics ----
// (no __threadfence -> no buffer_wbl2/inv -> L2 stays warm; all cross-block
//  data goes through sc-flagged atomic accesses instead)
__device__ __forceinline__ void gridbar(int* cnt, int* gen, int* my_gen) {
  __builtin_amdgcn_s_waitcnt(0);     // each wave drains its own global stores
  __syncthreads();
  if (threadIdx.x == 0) {
    int g = *my_gen;
    if (__hip_atomic_fetch_add(cnt, 1, __ATOMIC_RELAXED, __HIP_MEMORY_SCOPE_AGENT) == NBLK - 1) {
      __hip_atomic_store(cnt, 0, __ATOMIC_RELAXED, __HIP_MEMORY_SCOPE_AGENT);
      __hip_atomic_fetch_add(gen, 1, __ATOMIC_RELAXED, __HIP_MEMORY_SCOPE_AGENT);
    } else {
      while (__hip_atomic_load(gen, __ATOMIC_RELAXED, __HIP_MEMORY_SCOPE_AGENT) == g)
        __builtin_amdgcn_s_sleep(4);
    }
    *my_gen = g + 1;
  }
  __syncthreads();
}

// ---------------- one-shot f32 -> f16 casts (6 arrays) ----------------
struct CastJobs { const float* s[6]; f16* d[6]; int n4[6]; };
__global__ __launch_bounds__(256) void k_cast(CastJobs J) {
  int a = blockIdx.y;
  int i = blockIdx.x * 256 + threadIdx.x;
  if (i >= J.n4[a]) return;
  float4 v = ((const float4*)J.s[a])[i];
  v4h o; o[0] = (f16)v.x; o[1] = (f16)v.y; o[2] = (f16)v.z; o[3] = (f16)v.w;
  ((v4h*)J.d[a])[i] = o;
}

// ---------------- pack W1 = [dec_att_w | actv_w | whh] as f16 [512][4608] ----------------
__global__ __launch_bounds__(256) void k_pack(const float* __restrict__ dw,
    const float* __restrict__ aw, const float* __restrict__ ww,
    f16* __restrict__ W1) {
  int i4 = (blockIdx.x * 256 + threadIdx.x) * 4;
  int k = i4 / 4608, col = i4 % 4608;
  const float* src; int scol;
  if (col < 512)       { src = dw + (size_t)k * 512;  scol = col; }
  else if (col < 2560) { src = aw + (size_t)k * 2048; scol = col - 512; }
  else                 { src = ww + (size_t)k * 2048; scol = col - 2560; }
  float4 v = *(const float4*)(src + scol);
  v4h o; o[0] = (f16)v.x; o[1] = (f16)v.y; o[2] = (f16)v.z; o[3] = (f16)v.w;
  *(v4h*)(W1 + i4) = o;
}

// ---------------- mean over L ----------------
__global__ __launch_bounds__(256) void k_mean(const f16* __restrict__ inh,
                                              f16* __restrict__ meanh) {
  int b = blockIdx.x, tid = threadIdx.x;
  for (int e = tid; e < ENC_; e += 256) {
    float s = 0.f;
    for (int l = 0; l < L_; l++) s += (float)inh[((size_t)(b * L_ + l)) * ENC_ + e];
    meanh[b * ENC_ + e] = (f16)(s * (1.f / 49.f));
  }
}

// ---------------- shared 64x64 f16 MFMA tile helpers ----------------
__device__ __forceinline__ void stage_a64(const f16* src, int lda, f16 (*sA)[72], int tid) {
  int ar = tid >> 2, ak = (tid & 3) << 4;
  const f16* p = src + (size_t)ar * lda + ak;
  *(uint4*)&sA[ar][ak]     = *(const uint4*)p;
  *(uint4*)&sA[ar][ak + 8] = *(const uint4*)(p + 8);
}
// sc variant: for comm buffers (hh, xg) — reads through to the coherence point
__device__ __forceinline__ void stage_a64_sc(const f16* src, int lda, f16 (*sA)[72], int tid) {
  int ar = tid >> 2, ak = (tid & 3) << 4;
  const f16* p = src + (size_t)ar * lda + ak;
  unsigned long long a = ld_sc_u64(p), b = ld_sc_u64(p + 4);
  unsigned long long c = ld_sc_u64(p + 8), d = ld_sc_u64(p + 12);
  *(unsigned long long*)&sA[ar][ak]      = a;
  *(unsigned long long*)&sA[ar][ak + 4]  = b;
  *(unsigned long long*)&sA[ar][ak + 8]  = c;
  *(unsigned long long*)&sA[ar][ak + 12] = d;
}
__device__ __forceinline__ void stage_b64(const f16* src, int ldb, f16 (*sB)[72], int tid) {
  #pragma unroll
  for (int s = 0; s < 4; s++) {
    int slot = tid + s * 256;
    int kr = slot >> 4, nc = (slot & 15) << 2;
    v4h bl = *(const v4h*)(src + (size_t)kr * ldb + nc);
    sB[nc + 0][kr] = bl[0]; sB[nc + 1][kr] = bl[1];
    sB[nc + 2][kr] = bl[2]; sB[nc + 3][kr] = bl[3];
  }
}
__device__ __forceinline__ void mfma_tile(const f16 (*sA)[72], const f16 (*sB)[72],
                                          int fr, int fq, int wv, v4f* acc) {
  #pragma unroll
  for (int kk = 0; kk < 64; kk += 32) {
    v8h bfr = *(const v8h*)&sB[wv * 16 + fr][kk + fq * 8];
    #pragma unroll
    for (int mt = 0; mt < 4; mt++) {
      v8h afr = *(const v8h*)&sA[mt * 16 + fr][kk + fq * 8];
      acc[mt] = __builtin_amdgcn_mfma_f32_16x16x32_f16(afr, bfr, acc[mt], 0, 0, 0);
    }
  }
}

// ---------------- h0/c0 (MFMA) ----------------
__global__ __launch_bounds__(256) void k_h0c0(const f16* __restrict__ meanh,
    const f16* __restrict__ hw, const float* __restrict__ hb,
    const f16* __restrict__ cw, const float* __restrict__ cb,
    float* __restrict__ h, float* __restrict__ c, f16* __restrict__ hh) {
  __shared__ __align__(16) f16 sA[64][72], sB[64][72];
  int tid = threadIdx.x, lane = tid & 63, wv = tid >> 6, fr = lane & 15, fq = lane >> 4;
  int n0 = blockIdx.x * 64;
  bool ish = n0 < 512;
  const f16* W = ish ? hw : cw;
  const float* bb = ish ? hb : cb;
  int nb = ish ? n0 : (n0 - 512);
  v4f acc[4] = {};
  for (int k0 = 0; k0 < 2048; k0 += 64) {
    stage_a64(meanh + k0, 2048, sA, tid);
    stage_b64(W + (size_t)k0 * 512 + nb, 512, sB, tid);
    __syncthreads(); mfma_tile(sA, sB, fr, fq, wv, acc); __syncthreads();
  }
  int col = nb + wv * 16 + fr;
  float bv = bb[col];
  #pragma unroll
  for (int mt = 0; mt < 4; mt++)
    #pragma unroll
    for (int r = 0; r < 4; r++) {
      int b = mt * 16 + fq * 4 + r;
      float v = acc[mt][r] + bv;
      if (ish) { h[b * 512 + col] = v; hh[b * 512 + col] = (f16)v; }
      else       c[b * 512 + col] = v;
    }
}

// ---------------- enc_proj (MFMA, f16 out) ----------------
__global__ __launch_bounds__(256) void k_ep(const f16* __restrict__ inh,
    const f16* __restrict__ Wh, const float* __restrict__ bias,
    f16* __restrict__ out) {
  __shared__ __align__(16) f16 sA[64][72], sB[64][72];
  int tid = threadIdx.x, lane = tid & 63, wv = tid >> 6, fr = lane & 15, fq = lane >> 4;
  int m0 = blockIdx.x * 64, n0 = blockIdx.y * 64;
  v4f acc[4] = {};
  for (int k0 = 0; k0 < 2048; k0 += 64) {
    stage_a64(inh + (size_t)m0 * 2048 + k0, 2048, sA, tid);
    stage_b64(Wh + (size_t)k0 * 512 + n0, 512, sB, tid);
    __syncthreads(); mfma_tile(sA, sB, fr, fq, wv, acc); __syncthreads();
  }
  int col = n0 + wv * 16 + fr;
  float bv = bias[col];
  #pragma unroll
  for (int mt = 0; mt < 4; mt++)
    #pragma unroll
    for (int r = 0; r < 4; r++)
      out[(size_t)(m0 + mt * 16 + fq * 4 + r) * 512 + col] = (f16)(acc[mt][r] + bv);
}

// ---------------- emb gather (f16) ----------------
__global__ __launch_bounds__(256) void k_gather(const int* __restrict__ captions,
    const float* __restrict__ embw, f16* __restrict__ embx) {
  int t = blockIdx.x, b = blockIdx.y;
  int cap = captions[b * T_ + t];
  const float* src = embw + (size_t)cap * 512;
  f16* dst = embx + ((size_t)t * 64 + b) * 512;
  for (int i = threadIdx.x; i < 512; i += 256) dst[i] = (f16)src[i];
}

// ---------------- embproj = embx @ wih[0:512] + bih + bhh  (f16 out) ----------------
__global__ __launch_bounds__(256) void k_embproj(const f16* __restrict__ embx,
    const f16* __restrict__ wih_h, const float* __restrict__ bih,
    const float* __restrict__ bhh, f16* __restrict__ embproj) {
  __shared__ __align__(16) f16 sA[64][72], sB[64][72];
  int tid = threadIdx.x, lane = tid & 63, wv = tid >> 6, fr = lane & 15, fq = lane >> 4;
  int m0 = blockIdx.x * 64, n0 = blockIdx.y * 64;
  v4f acc[4] = {};
  for (int k0 = 0; k0 < 512; k0 += 64) {
    stage_a64(embx + (size_t)m0 * 512 + k0, 512, sA, tid);
    stage_b64(wih_h + (size_t)k0 * 2048 + n0, 2048, sB, tid);
    __syncthreads(); mfma_tile(sA, sB, fr, fq, wv, acc); __syncthreads();
  }
  int col = n0 + wv * 16 + fr;
  float bv = bih[col] + bhh[col];
  #pragma unroll
  for (int mt = 0; mt < 4; mt++)
    #pragma unroll
    for (int r = 0; r < 4; r++)
      embproj[(size_t)(m0 + mt * 16 + fq * 4 + r) * 2048 + col] = (f16)(acc[mt][r] + bv);
}

// ---------------- persistent recurrence (fence-free barrier + sc comm) ----------------
__global__ __launch_bounds__(256) void k_loop(
    const f16* __restrict__ input_h, const f16* __restrict__ encproj,
    const f16* __restrict__ W1, const f16* __restrict__ wih2,
    const f16* __restrict__ embproj, const float* __restrict__ att_w,
    const float* __restrict__ att_b, const float* __restrict__ dab,
    const float* __restrict__ avb, const int* __restrict__ lens,
    const float* __restrict__ h0, const float* __restrict__ c0,
    f16* __restrict__ hh,
    float* __restrict__ pp1, f16* __restrict__ xg, float* __restrict__ q,
    f16* __restrict__ hseq, float* __restrict__ probs, int* bar) {
  __shared__ __align__(16) f16 sA[64][72], sB[64][72];
  __shared__ float sd[512], sw[512], ss[64], sp[64];
  int bid = blockIdx.x, tid = threadIdx.x;
  int lane = tid & 63, wv = tid >> 6, fr = lane & 15, fq = lane >> 4;
  int* cnt = bar; int* gen = bar + 1;
  int my_gen = 0;

  if (bid < 128)
    for (int i = tid; i < 512; i += 256) sw[i] = att_w[i];
  float attb = att_b[0];

  // P4 state: h,c live in registers across all 59 steps (stable thread->(b,d) map)
  float hP[2][2], cP[2][2];
  if (bid < 32) {
    #pragma unroll
    for (int it = 0; it < 2; it++) {
      int b = bid * 2 + it, d = tid * 2;
      hP[it][0] = h0[b * 512 + d]; hP[it][1] = h0[b * 512 + d + 1];
      cP[it][0] = c0[b * 512 + d]; cP[it][1] = c0[b * 512 + d + 1];
    }
  }

  for (int t = 0; t < TM_; t++) {
    // ---- P1 (144 blocks): pp1[z] = hh[:, z*256:+256] @ W1[z rows][4608] ----
    {
      int z = bid & 1, n0 = (bid >> 1) * 64;
      v4f acc[4] = {};
      #pragma unroll
      for (int ch = 0; ch < 4; ch++) {
        int k0 = z * 256 + ch * 64;
        stage_a64_sc(hh + k0, 512, sA, tid);
        stage_b64(W1 + (size_t)k0 * 4608 + n0, 4608, sB, tid);
        __syncthreads(); mfma_tile(sA, sB, fr, fq, wv, acc); __syncthreads();
      }
      int col = n0 + wv * 16 + fr;
      float* pp = pp1 + (size_t)z * 64 * 4608;
      #pragma unroll
      for (int mt = 0; mt < 4; mt++)
        #pragma unroll
        for (int r = 0; r < 4; r++)
          st_sc_f32(&pp[(size_t)(mt * 16 + fq * 4 + r) * 4608 + col], acc[mt][r]);
    }
    gridbar(cnt, gen, &my_gen);
    // ---- P2 (128 blocks): attention + x staging ----
    if (bid < 128) {
      int b = bid >> 1, half = bid & 1;
      for (int i = tid; i < 512; i += 256)
        sd[i] = ld_sc_f32(&pp1[b * 4608 + i])
              + ld_sc_f32(&pp1[(size_t)64 * 4608 + b * 4608 + i]) + dab[i];
      __syncthreads();
      for (int l = wv; l < L_; l += 4) {
        const f16* ep = encproj + (size_t)(b * L_ + l) * 512;
        float p = 0.f;
        #pragma unroll
        for (int i = 0; i < 8; i++) {
          int a = lane + i * 64;
          float v = (float)ep[a] + sd[a];
          p = fmaf(fmaxf(v, 0.f), sw[a], p);
        }
        #pragma unroll
        for (int off = 32; off > 0; off >>= 1) p += __shfl_xor(p, off);
        if (lane == 0) ss[l] = p;
      }
      __syncthreads();
      if (wv == 0) {
        float v = (lane < L_) ? (ss[lane] + attb) : -3.0e38f;
        float m = v;
        #pragma unroll
        for (int off = 32; off > 0; off >>= 1) m = fmaxf(m, __shfl_xor(m, off));
        float e = (lane < L_) ? __expf(v - m) : 0.f;
        float s = e;
        #pragma unroll
        for (int off = 32; off > 0; off >>= 1) s += __shfl_xor(s, off);
        float pr = e / s;
        if (lane < L_) {
          sp[lane] = pr;
          if (half == 0) {
            bool act = t < (lens[b] - 1);
            probs[((size_t)b * TM_ + t) * L_ + lane] = act ? pr : 0.f;
          }
        }
      }
      __syncthreads();
      int c = half * 1024 + tid * 4;
      const f16* ip = input_h + (size_t)b * L_ * 2048 + c;
      float a0 = 0, a1 = 0, a2 = 0, a3 = 0;
      for (int l = 0; l < L_; l++) {
        v4h x = *(const v4h*)(ip + (size_t)l * 2048);
        float pl = sp[l];
        a0 = fmaf(pl, (float)x[0], a0); a1 = fmaf(pl, (float)x[1], a1);
        a2 = fmaf(pl, (float)x[2], a2); a3 = fmaf(pl, (float)x[3], a3);
      }
      const float* g0 = pp1 + b * 4608 + 512 + c;
      const float* g1 = pp1 + (size_t)64 * 4608 + b * 4608 + 512 + c;
      float2 u01 = u64_f2(ld_sc_u64(g0)), u23 = u64_f2(ld_sc_u64(g0 + 2));
      float2 v01 = u64_f2(ld_sc_u64(g1)), v23 = u64_f2(ld_sc_u64(g1 + 2));
      float4 ab = *(const float4*)(avb + c);
      v4h o;
      o[0] = (f16)(a0 * sigmoidf_(u01.x + v01.x + ab.x));
      o[1] = (f16)(a1 * sigmoidf_(u01.y + v01.y + ab.y));
      o[2] = (f16)(a2 * sigmoidf_(u23.x + v23.x + ab.z));
      o[3] = (f16)(a3 * sigmoidf_(u23.y + v23.y + ab.w));
      unsigned long long ou; __builtin_memcpy(&ou, &o, 8);
      st_sc_u64(xg + b * 2048 + c, ou);
    }
    gridbar(cnt, gen, &my_gen);
    // ---- P3 (128 blocks): q[z] = xg[:, z*512:+512] @ wih2[z rows] ----
    if (bid < 128) {
      int z = bid & 3, n0 = (bid >> 2) * 64;
      v4f acc[4] = {};
      #pragma unroll
      for (int ch = 0; ch < 8; ch++) {
        int k0 = z * 512 + ch * 64;
        stage_a64_sc(xg + k0, 2048, sA, tid);
        stage_b64(wih2 + (size_t)k0 * 2048 + n0, 2048, sB, tid);
        __syncthreads(); mfma_tile(sA, sB, fr, fq, wv, acc); __syncthreads();
      }
      int col = n0 + wv * 16 + fr;
      float* qq = q + (size_t)z * 64 * 2048;
      #pragma unroll
      for (int mt = 0; mt < 4; mt++)
        #pragma unroll
        for (int r = 0; r < 4; r++)
          st_sc_f32(&qq[(size_t)(mt * 16 + fq * 4 + r) * 2048 + col], acc[mt][r]);
    }
    gridbar(cnt, gen, &my_gen);
    // ---- P4 (32 blocks): reduce + cell update (h,c in registers) ----
    if (bid < 32) {
      #pragma unroll
      for (int it = 0; it < 2; it++) {
        int b = bid * 2 + it, d = tid * 2;
        float g[4][2];
        #pragma unroll
        for (int gate = 0; gate < 4; gate++) {
          int n = gate * 512 + d;
          float2 e = f16x2_f2(*(const uint32_t*)(embproj + ((size_t)t * 64 + b) * 2048 + n));
          float2 w1 = u64_f2(ld_sc_u64(pp1 + b * 4608 + 2560 + n));
          float2 w2 = u64_f2(ld_sc_u64(pp1 + (size_t)64 * 4608 + b * 4608 + 2560 + n));
          float sx = e.x + w1.x + w2.x, sy = e.y + w1.y + w2.y;
          #pragma unroll
          for (int z = 0; z < 4; z++) {
            float2 qq = u64_f2(ld_sc_u64(q + ((size_t)z * 64 + b) * 2048 + n));
            sx += qq.x; sy += qq.y;
          }
          g[gate][0] = sx; g[gate][1] = sy;
        }
        bool act = t < (lens[b] - 1);
        #pragma unroll
        for (int j = 0; j < 2; j++) {
          float i_ = sigmoidf_(g[0][j]), f_ = sigmoidf_(g[1][j]);
          float gg = tanhf_(g[2][j]), o_ = sigmoidf_(g[3][j]);
          float cn = f_ * cP[it][j] + i_ * gg;
          float hn = o_ * tanhf_(cn);
          if (act) { cP[it][j] = cn; hP[it][j] = hn; }
        }
        uint32_t hp = pack_f16x2(hP[it][0], hP[it][1]);
        st_sc_u32(hh + b * 512 + d, hp);
        *(uint32_t*)(hseq + ((size_t)t * 64 + b) * 512 + d) = hp;
      }
    }
    gridbar(cnt, gen, &my_gen);
  }
}

// ---------------- final fc GEMM ----------------
__global__ __launch_bounds__(256) void k_fc(const f16* __restrict__ hseq,
    const f16* __restrict__ W, const float* __restrict__ bias,
    const int* __restrict__ lens, float* __restrict__ preds) {
  __shared__ __align__(16) f16 sA[64][72], sB[64][72];
  int tid = threadIdx.x, lane = tid & 63, wv = tid >> 6, fr = lane & 15, fq = lane >> 4;
  int t = blockIdx.x, n0 = blockIdx.y * 64;
  v4f acc[4] = {};
  for (int k0 = 0; k0 < 512; k0 += 64) {
    stage_a64(hseq + ((size_t)t * 64) * 512 + k0, 512, sA, tid);
    #pragma unroll
    for (int s = 0; s < 4; s++) {
      int slot = tid + s * 256;
      int kr = slot >> 4, nc = (slot & 15) << 2;
      int colb = n0 + nc;
      const f16* bp = W + (size_t)(k0 + kr) * V_;
      f16 e0, e1, e2, e3;
      if (colb + 3 < V_) {
        v4h bl = *(const v4h*)(bp + colb);
        e0 = bl[0]; e1 = bl[1]; e2 = bl[2]; e3 = bl[3];
      } else {
        e0 = (colb + 0 < V_) ? bp[colb + 0] : (f16)0.f;
        e1 = (colb + 1 < V_) ? bp[colb + 1] : (f16)0.f;
        e2 = (colb + 2 < V_) ? bp[colb + 2] : (f16)0.f;
        e3 = (colb + 3 < V_) ? bp[colb + 3] : (f16)0.f;
      }
      sB[nc + 0][kr] = e0; sB[nc + 1][kr] = e1; sB[nc + 2][kr] = e2; sB[nc + 3][kr] = e3;
    }
    __syncthreads(); mfma_tile(sA, sB, fr, fq, wv, acc); __syncthreads();
  }
  int col = n0 + wv * 16 + fr;
  if (col < V_) {
    float bv = bias[col];
    #pragma unroll
    for (int mt = 0; mt < 4; mt++)
      #pragma unroll
      for (int r = 0; r < 4; r++) {
        int b = mt * 16 + fq * 4 + r;
        bool act = t < (lens[b] - 1);
        preds[((size_t)b * TM_ + t) * (size_t)V_ + col] = act ? (acc[mt][r] + bv) : 0.f;
      }
  }
}

extern "C" void kernel_launch(void* const* d_in, const int* in_sizes, int n_in,
                              void* d_out, int out_size, void* d_ws, size_t ws_size,
                              hipStream_t stream) {
  (void)in_sizes; (void)n_in; (void)out_size; (void)ws_size;
  const float* input     = (const float*)d_in[0];
  const int*   captions  = (const int*)d_in[1];
  const int*   lens      = (const int*)d_in[2];
  const float* embw      = (const float*)d_in[3];
  const float* enc_att_w = (const float*)d_in[4];
  const float* enc_att_b = (const float*)d_in[5];
  const float* dec_att_w = (const float*)d_in[6];
  const float* dec_att_b = (const float*)d_in[7];
  const float* att_w     = (const float*)d_in[8];
  const float* att_b     = (const float*)d_in[9];
  const float* h_w       = (const float*)d_in[10];
  const float* h_b       = (const float*)d_in[11];
  const float* c_w       = (const float*)d_in[12];
  const float* c_b       = (const float*)d_in[13];
  const float* actv_w    = (const float*)d_in[14];
  const float* actv_b    = (const float*)d_in[15];
  const float* wih       = (const float*)d_in[16];
  const float* whh       = (const float*)d_in[17];
  const float* bih       = (const float*)d_in[18];
  const float* bhh       = (const float*)d_in[19];
  const float* fc_w      = (const float*)d_in[20];
  const float* fc_b      = (const float*)d_in[21];

  float* preds = (float*)d_out;
  float* probs = preds + (size_t)B_ * TM_ * V_;

  char* w = (char*)d_ws;
  auto alloc = [&](size_t bytes) -> char* {
    char* p = w; w += (bytes + 255) & ~(size_t)255; return p;
  };
  int* bar     = (int*)alloc(256);
  f16* input_h = (f16*)alloc((size_t)6422528 * 2);
  f16* eaw_h   = (f16*)alloc((size_t)1048576 * 2);
  f16* wih_h   = (f16*)alloc((size_t)5242880 * 2);
  f16* hw_h    = (f16*)alloc((size_t)1048576 * 2);
  f16* cw_h    = (f16*)alloc((size_t)1048576 * 2);
  f16* fcw_h   = (f16*)alloc((size_t)5120000 * 2);
  f16* W1      = (f16*)alloc((size_t)2359296 * 2);
  f16* meanh   = (f16*)alloc((size_t)B_ * ENC_ * 2);
  f16* encproj = (f16*)alloc((size_t)3136 * 512 * 2);
  f16* embx    = (f16*)alloc((size_t)3776 * 512 * 2);
  f16* embproj = (f16*)alloc((size_t)3776 * 2048 * 2);
  float* hf    = (float*)alloc((size_t)B_ * 512 * 4);
  float* cf    = (float*)alloc((size_t)B_ * 512 * 4);
  f16*   hh    = (f16*)alloc((size_t)B_ * 512 * 2);
  float* pp1   = (float*)alloc((size_t)2 * 64 * 4608 * 4);
  f16*   xg    = (f16*)alloc((size_t)B_ * 2048 * 2);
  float* q     = (float*)alloc((size_t)4 * 64 * 2048 * 4);
  f16*   hseq  = (f16*)alloc((size_t)TM_ * 64 * 512 * 2);

  hipMemsetAsync(bar, 0, 8, stream);

  CastJobs J;
  J.s[0] = input; J.d[0] = input_h; J.n4[0] = 6422528 / 4;
  J.s[1] = enc_att_w; J.d[1] = eaw_h; J.n4[1] = 1048576 / 4;
  J.s[2] = wih; J.d[2] = wih_h; J.n4[2] = 5242880 / 4;
  J.s[3] = h_w; J.d[3] = hw_h; J.n4[3] = 1048576 / 4;
  J.s[4] = c_w; J.d[4] = cw_h; J.n4[4] = 1048576 / 4;
  J.s[5] = fc_w; J.d[5] = fcw_h; J.n4[5] = 5120000 / 4;
  k_cast<<<dim3((1605632 + 255) / 256, 6), 256, 0, stream>>>(J);
  k_pack<<<2304, 256, 0, stream>>>(dec_att_w, actv_w, whh, W1);
  k_mean<<<64, 256, 0, stream>>>(input_h, meanh);
  k_h0c0<<<16, 256, 0, stream>>>(meanh, hw_h, h_b, cw_h, c_b, hf, cf, hh);
  k_ep<<<dim3(49, 8), 256, 0, stream>>>(input_h, eaw_h, enc_att_b, encproj);
  k_gather<<<dim3(59, 64), 256, 0, stream>>>(captions, embw, embx);
  k_embproj<<<dim3(59, 32), 256, 0, stream>>>(embx, wih_h, bih, bhh, embproj);

  const f16* wih2 = wih_h + (size_t)512 * 2048;
  k_loop<<<NBLK, 256, 0, stream>>>(input_h, encproj, W1, wih2, embproj,
                                   att_w, att_b, dec_att_b, actv_b, lens,
                                   hf, cf, hh, pp1, xg, q, hseq, probs, bar);

  k_fc<<<dim3(59, 157), 256, 0, stream>>>(hseq, fcw_h, fc_b, lens, preds);
}